// Round 1
// 143.938 us; speedup vs baseline: 1.0062x; 1.0062x over previous
//
#include <hip/hip_runtime.h>

// Problem constants (match reference file)
constexpr int   NUM_CLAUSES = 1000000;
constexpr int   NUM_EDGES   = 3000000;   // per polarity
constexpr float Pc = 5.0f;
constexpr float Ac = 10.0f;

// Clause-accumulator packing: low 16 bits = num * 2^6, high 16 = den * 2^6.
// Exactly 3 pos + 3 neg edges per clause; each term <= e^5 = 148.413 ->
// max field sum 6*148.413*64 = 56,990 < 65,536: no overflow, no lo->hi carry.
constexpr float FXSCALE = 64.0f;
constexpr float FXINV   = 1.0f / 64.0f;

// Bucketing: 500 buckets x 2000 clauses. Each clause contributes EXACTLY
// 3 pos + 3 neg records -> bucket holds EXACTLY 12,000 records (both pol).
// (500 buckets -> bucket grid gets 2 blocks/CU instead of <1.)
constexpr int NB  = 500;
constexpr int CPB = 2000;           // clauses per bucket (fits 11 bits)
constexpr int CAP = CPB * 6;        // 12000 records per bucket

// Partition geometry: 1024 threads, 8192 records per block, 8 per thread.
// 1024-thread blocks -> 2 blocks/CU resident (32 waves/CU, was ~13).
constexpr int TPB   = 1024;
constexpr int RPB   = 8192;
constexpr int RPT   = RPB / TPB;    // 8
constexpr int NBLKP = (NUM_EDGES + RPB - 1) / RPB;   // 367 blocks / polarity

// Record format (u32): lit quantized to 20 bits << 11 | local clause (11 bits).
// Polarity already applied to lit, so pos/neg records are interchangeable.
// QSCALE unchanged from previous passing kernel -> bit-identical numerics.
constexpr float QSCALE = 1048575.0f;    // 2^20 - 1
constexpr float QINV   = 1.0f / 1048575.0f;

// Reservation counters padded to one per 64B line: the old layout packed 250
// counters into ~16 lines -> ~11.7K same-line cross-XCD atomic RMWs per line.
constexpr int CSTRIDE = 16;         // u32 stride = 64 bytes

// Workspace layout (bytes):
//   recs     u32[NB*CAP]     = 24,000,000  @ 0
//   counters u32[NB*CSTRIDE] =     32,000  @ 24,000,000
//   partials f32[NB]         =      2,000  @ 24,032,000
constexpr size_t OFF_CTR = 24000000;
constexpr size_t OFF_PAR = OFF_CTR + (size_t)NB * CSTRIDE * 4;

__device__ __forceinline__ unsigned pack_fx(float num, float den) {
    unsigned lo = (unsigned)(num * FXSCALE + 0.5f);
    unsigned hi = (unsigned)(den * FXSCALE + 0.5f);
    return lo | (hi << 16);
}

// ---------------------------------------------------------------------------
// Partition BOTH polarities' 6M edge records into NB clause-range buckets.
// Grid = 2*NBLKP: first half reads adj_pos, second half adj_neg (lit = 1-x).
// Ordering is arranged so the three long-latency operations overlap:
//   - x gathers are issued before the LDS hist-rank atomics (rank loop only
//     needs clause ids),
//   - the contended global reservation atomic is issued right after the scan
//     and its result is consumed only AFTER record build + LDS staging,
//   - staggered counter order + 64B padding de-convoys the reservation.
// ---------------------------------------------------------------------------
__global__ __launch_bounds__(TPB, 8)
void partition_kernel(const int*   __restrict__ adj_pos,
                      const int*   __restrict__ adj_neg,
                      const float* __restrict__ x,
                      unsigned* __restrict__ recs,
                      unsigned* __restrict__ counters) {
    __shared__ unsigned       hist[NB];
    __shared__ unsigned       sbase[NB];    // global reservation base
    __shared__ unsigned       lbase[NB];    // block-local exclusive scan
    __shared__ unsigned       srec[RPB];    // 32 KB staging, bucket-sorted
    __shared__ unsigned short sbid[RPB];    // 16 KB bucket id per staged slot
    __shared__ unsigned       wsum[TPB / 64];
    __shared__ unsigned       woff[TPB / 64];

    const bool neg   = (blockIdx.x >= (unsigned)NBLKP);
    const int  sblk  = neg ? (int)blockIdx.x - NBLKP : (int)blockIdx.x;
    const int  start = sblk * RPB;
    const int  n     = min(RPB, NUM_EDGES - start);
    const int* crow  = neg ? adj_neg : adj_pos;
    const int* vrow  = crow + NUM_EDGES;
    const int  tid   = (int)threadIdx.x;

    if (tid < NB) hist[tid] = 0;
    __syncthreads();

    // ---- load adjacency (vectorized) ----
    int cc_[RPT], vv_[RPT];
    if (n == RPB) {
        #pragma unroll
        for (int j = 0; j < RPT / 4; ++j) {
            int4 c4 = ((const int4*)(crow + start))[j * TPB + tid];
            int4 v4 = ((const int4*)(vrow + start))[j * TPB + tid];
            cc_[4*j] = c4.x; cc_[4*j+1] = c4.y; cc_[4*j+2] = c4.z; cc_[4*j+3] = c4.w;
            vv_[4*j] = v4.x; vv_[4*j+1] = v4.y; vv_[4*j+2] = v4.z; vv_[4*j+3] = v4.w;
        }
    } else {
        #pragma unroll
        for (int r = 0; r < RPT; ++r) {
            int pos = 4 * ((r >> 2) * TPB + tid) + (r & 3);
            cc_[r] = (pos < n) ? crow[start + pos] : -1;
            vv_[r] = (pos < n) ? vrow[start + pos] : 0;
        }
    }

    // ---- issue x gathers EARLY; results consumed only after the scan ----
    float xv[RPT];
    #pragma unroll
    for (int r = 0; r < RPT; ++r) xv[r] = x[vv_[r]];

    // ---- hist-rank atomics (clause ids only; overlaps gather latency) ----
    unsigned meta[RPT];   // meta = b<<13 | rank (0xFFFFFFFF inactive)
    #pragma unroll
    for (int r = 0; r < RPT; ++r) {
        meta[r] = 0xFFFFFFFFu;
        if (cc_[r] >= 0) {
            int b = cc_[r] / CPB;
            unsigned rank = atomicAdd(&hist[b], 1u);
            meta[r] = ((unsigned)b << 13) | rank;
        }
    }
    __syncthreads();

    // ---- block-local exclusive scan of hist (wave shuffles) ----
    unsigned h    = (tid < NB) ? hist[tid] : 0u;
    unsigned incl = h;
    #pragma unroll
    for (int off = 1; off < 64; off <<= 1) {
        unsigned t = __shfl_up(incl, off, 64);
        if ((tid & 63) >= off) incl += t;
    }
    if ((tid & 63) == 63) wsum[tid >> 6] = incl;
    __syncthreads();
    if (tid == 0) {
        unsigned a = 0;
        #pragma unroll
        for (int w = 0; w < TPB / 64; ++w) { woff[w] = a; a += wsum[w]; }
    }
    __syncthreads();
    if (tid < NB) lbase[tid] = incl - h + woff[tid >> 6];
    __syncthreads();

    // ---- issue global reservation atomic (staggered, padded 64B lines).
    //      Result is NOT consumed until after staging -> latency overlapped.
    unsigned myres = 0;
    int      rb    = 0;
    if (tid < NB) {
        int boff = (int)blockIdx.x;
        if (boff >= NB) boff -= NB;            // blockIdx < 2*NB
        rb = tid + boff;
        if (rb >= NB) rb -= NB;
        myres = atomicAdd(&counters[rb * CSTRIDE], hist[rb]);
    }

    // ---- build records (first xv use -> gather wait lands here) and stage
    //      into LDS bucket-sorted ----
    #pragma unroll
    for (int r = 0; r < RPT; ++r) {
        if (cc_[r] >= 0) {
            unsigned b    = meta[r] >> 13;
            unsigned rank = meta[r] & 0x1FFFu;
            int      loc  = cc_[r] - (int)b * CPB;
            float    lit  = neg ? (1.0f - xv[r]) : xv[r];
            unsigned q    = (unsigned)(lit * QSCALE + 0.5f);
            unsigned p    = lbase[b] + rank;
            srec[p] = (q << 11) | (unsigned)loc;
            sbid[p] = (unsigned short)b;
        }
    }
    if (tid < NB) sbase[rb] = myres;   // wait on reservation return here
    __syncthreads();

    // ---- coalesced writeout (consecutive p -> consecutive global) ----
    for (int p = tid; p < n; p += TPB) {
        unsigned b = sbid[p];
        recs[(size_t)b * CAP + sbase[b] + ((unsigned)p - lbase[b])] = srec[p];
    }
}

// ---------------------------------------------------------------------------
// Bucket phase: one block per bucket (500 blocks -> 2 per CU). Stream 12,000
// records (uint4 loads), recompute w = exp(P*lit), accumulate packed (num,den)
// via LDS atomics, then decode, sigmoid + squared error, block-reduce.
// ---------------------------------------------------------------------------
__global__ __launch_bounds__(1024, 8)
void bucket_loss_kernel(const uint4* __restrict__ recs4,
                        const float* __restrict__ cc,
                        float* __restrict__ partials) {
    __shared__ unsigned lacc[CPB];   // 8 KB
    const int b = blockIdx.x;
    for (int j = threadIdx.x; j < CPB; j += 1024) lacc[j] = 0;
    __syncthreads();

    const uint4* r4 = recs4 + (size_t)b * (CAP / 4);
    for (int k = threadIdx.x; k < CAP / 4; k += 1024) {
        uint4 e = r4[k];
        #pragma unroll
        for (int k2 = 0; k2 < 4; ++k2) {
            unsigned r  = (&e.x)[k2];
            float lit = (float)(r >> 11) * QINV;
            float w   = __expf(Pc * lit);
            atomicAdd(&lacc[r & 0x7FFu], pack_fx(lit * w, w));
        }
    }
    __syncthreads();

    float v = 0.0f;
    const float* gc = cc + (size_t)b * CPB;
    for (int j = threadIdx.x; j < CPB; j += 1024) {
        unsigned a   = lacc[j];                 // packed fields can't overflow
        float    num = (float)(a & 0xffffu) * FXINV;
        float    den = (float)(a >> 16)     * FXINV;
        float    sm  = 1.0f / (1.0f + __expf(-Ac * (num / den - 0.5f)));
        float    e0  = sm - gc[j];
        v += e0 * e0;
    }
    v *= 1.0f / (float)NUM_CLAUSES;

    #pragma unroll
    for (int off = 32; off > 0; off >>= 1)
        v += __shfl_down(v, off, 64);

    __shared__ float partial[16];   // 1024 threads = 16 waves
    int lane = threadIdx.x & 63;
    int wid  = threadIdx.x >> 6;
    if (lane == 0) partial[wid] = v;
    __syncthreads();
    if (threadIdx.x == 0) {
        float s = 0.f;
        #pragma unroll
        for (int w = 0; w < 16; ++w) s += partial[w];
        partials[b] = s;
    }
}

// ---------------------------------------------------------------------------
// Final reduce: ONE block sums NB partials, plain-stores out[0].
// ---------------------------------------------------------------------------
__global__ void final_kernel(const float* __restrict__ partials,
                             float* __restrict__ out, int n) {
    float v = 0.0f;
    for (int i = threadIdx.x; i < n; i += 256) v += partials[i];

    #pragma unroll
    for (int off = 32; off > 0; off >>= 1)
        v += __shfl_down(v, off, 64);

    __shared__ float partial[4];
    int lane = threadIdx.x & 63;
    int wid  = threadIdx.x >> 6;
    if (lane == 0) partial[wid] = v;
    __syncthreads();
    if (threadIdx.x == 0)
        out[0] = partial[0] + partial[1] + partial[2] + partial[3];
}

// ---------------------------------------------------------------------------
extern "C" void kernel_launch(void* const* d_in, const int* in_sizes, int n_in,
                              void* d_out, int out_size, void* d_ws, size_t ws_size,
                              hipStream_t stream) {
    const float* xv      = (const float*)d_in[0];   // [V] fp32
    const int*   adj_pos = (const int*)  d_in[1];   // [2,E] int32
    const int*   adj_neg = (const int*)  d_in[2];   // [2,E] int32
    const float* cc      = (const float*)d_in[3];   // [C] fp32 (ones)

    char* ws = (char*)d_ws;
    unsigned* recs     = (unsigned*)ws;
    unsigned* counters = (unsigned*)(ws + OFF_CTR);
    float*    partials = (float*)   (ws + OFF_PAR);
    float*    out      = (float*)d_out;

    // 1) zero padded bucket counters (32 KB)
    hipMemsetAsync(counters, 0, (size_t)NB * CSTRIDE * sizeof(unsigned), stream);

    // 2) partition both polarities into bucketed u32 records (LDS-reordered,
    //    coalesced writeout)
    partition_kernel<<<2 * NBLKP, TPB, 0, stream>>>(adj_pos, adj_neg, xv,
                                                    recs, counters);

    // 3) per-bucket LDS accumulate + loss -> one partial per bucket
    bucket_loss_kernel<<<NB, 1024, 0, stream>>>((const uint4*)recs, cc, partials);

    // 4) single-block final reduce -> out[0]
    final_kernel<<<1, 256, 0, stream>>>(partials, out, NB);
}

// Round 2
// 139.901 us; speedup vs baseline: 1.0353x; 1.0289x over previous
//
#include <hip/hip_runtime.h>

// Problem constants (match reference file)
constexpr int   NUM_CLAUSES = 1000000;
constexpr int   NUM_EDGES   = 3000000;   // per polarity
constexpr float Pc = 5.0f;
constexpr float Ac = 10.0f;

// Clause-accumulator packing: low 16 bits = num * 2^6, high 16 = den * 2^6.
// Exactly 3 pos + 3 neg edges per clause; each term <= e^5 = 148.413 ->
// max field sum 6*148.413*64 = 56,990 < 65,536: no overflow, no lo->hi carry.
constexpr float FXSCALE = 64.0f;
constexpr float FXINV   = 1.0f / 64.0f;

// Bucketing: 500 buckets x 2000 clauses -> bucket grid = 2 blocks/CU.
constexpr int NB  = 500;
constexpr int CPB = 2000;           // clauses per bucket (fits 11 bits)
constexpr int CAP = CPB * 6;        // 12000 records per bucket (exact: 3+3/clause)

// Partition geometry: 1024 threads, 12288 records per block, 12 per thread.
// LDS/block ~78 KB -> 2 blocks/CU (32 waves). Longer per-bucket runs
// (avg 24.6 recs = 98 B) cut the write amplification seen at RPB=8192.
constexpr int TPB   = 1024;
constexpr int RPB   = 12288;
constexpr int RPT   = RPB / TPB;    // 12
constexpr int NBLKP = (NUM_EDGES + RPB - 1) / RPB;   // 245 blocks / polarity

// Record format (u32): variable index (20b) << 12 | polarity (1b) << 11 |
// local clause (11b). NO x gather in partition: the bucket kernel gathers x
// and reproduces the exact quantize->pack pipeline (bit-identical numerics).
constexpr float QSCALE = 1048575.0f;    // 2^20 - 1
constexpr float QINV   = 1.0f / 1048575.0f;

// Reservation counters padded to one per 64B line.
constexpr int CSTRIDE = 16;         // u32 stride = 64 bytes

// Workspace layout (bytes):
//   recs     u32[NB*CAP]     = 24,000,000  @ 0
//   counters u32[NB*CSTRIDE] =     32,000  @ 24,000,000
//   partials f32[NB]         =      2,000  @ 24,032,000
constexpr size_t OFF_CTR = 24000000;
constexpr size_t OFF_PAR = OFF_CTR + (size_t)NB * CSTRIDE * 4;

__device__ __forceinline__ unsigned pack_fx(float num, float den) {
    unsigned lo = (unsigned)(num * FXSCALE + 0.5f);
    unsigned hi = (unsigned)(den * FXSCALE + 0.5f);
    return lo | (hi << 16);
}

// ---------------------------------------------------------------------------
// Partition BOTH polarities' 6M edge records into NB clause-range buckets.
// Grid = 2*NBLKP: first half reads adj_pos, second half adj_neg.
// CRITICAL-PATH CHANGE vs previous round: records carry the variable INDEX,
// not the literal value -> partition performs ZERO random gathers. Its
// critical path is now coalesced adjacency loads + LDS hist + scan + staging.
// ---------------------------------------------------------------------------
__global__ __launch_bounds__(TPB, 8)
void partition_kernel(const int*   __restrict__ adj_pos,
                      const int*   __restrict__ adj_neg,
                      unsigned* __restrict__ recs,
                      unsigned* __restrict__ counters) {
    // hist_sbase: used as per-bucket histogram, then re-used (same element,
    // same owning thread, barrier-fenced) as the global reservation base.
    __shared__ unsigned       hist_sbase[NB];
    __shared__ unsigned       lbase[NB];    // block-local exclusive scan
    __shared__ unsigned       srec[RPB];    // 48 KB staging, bucket-sorted
    __shared__ unsigned short sbid[RPB];    // 24 KB bucket id per staged slot
    __shared__ unsigned       wsum[TPB / 64];
    __shared__ unsigned       woff[TPB / 64];

    const bool neg   = (blockIdx.x >= (unsigned)NBLKP);
    const int  sblk  = neg ? (int)blockIdx.x - NBLKP : (int)blockIdx.x;
    const int  start = sblk * RPB;
    const int  n     = min(RPB, NUM_EDGES - start);
    const int* crow  = neg ? adj_neg : adj_pos;
    const int* vrow  = crow + NUM_EDGES;
    const int  tid   = (int)threadIdx.x;
    const unsigned polbit = neg ? 0x800u : 0u;

    if (tid < NB) hist_sbase[tid] = 0;
    __syncthreads();

    // ---- load adjacency (vectorized int4, fully coalesced) ----
    int cc_[RPT], vv_[RPT];
    if (n == RPB) {
        #pragma unroll
        for (int j = 0; j < RPT / 4; ++j) {
            int4 c4 = ((const int4*)(crow + start))[j * TPB + tid];
            cc_[4*j] = c4.x; cc_[4*j+1] = c4.y; cc_[4*j+2] = c4.z; cc_[4*j+3] = c4.w;
        }
        #pragma unroll
        for (int j = 0; j < RPT / 4; ++j) {
            int4 v4 = ((const int4*)(vrow + start))[j * TPB + tid];
            vv_[4*j] = v4.x; vv_[4*j+1] = v4.y; vv_[4*j+2] = v4.z; vv_[4*j+3] = v4.w;
        }
    } else {
        #pragma unroll
        for (int r = 0; r < RPT; ++r) {
            int pos = 4 * ((r >> 2) * TPB + tid) + (r & 3);
            cc_[r] = (pos < n) ? crow[start + pos] : -1;
            vv_[r] = (pos < n) ? vrow[start + pos] : 0;
        }
    }

    // ---- hist-rank atomics (needs clause ids only; v loads still in flight)
    unsigned meta[RPT];   // meta = b<<14 | rank (valid only where cc_>=0)
    #pragma unroll
    for (int r = 0; r < RPT; ++r) {
        meta[r] = 0;
        if (cc_[r] >= 0) {
            int b = cc_[r] / CPB;
            unsigned rank = atomicAdd(&hist_sbase[b], 1u);
            meta[r] = ((unsigned)b << 14) | rank;
        }
    }
    __syncthreads();

    // ---- block-local exclusive scan of hist (wave shuffles) ----
    unsigned h    = (tid < NB) ? hist_sbase[tid] : 0u;
    unsigned incl = h;
    #pragma unroll
    for (int off = 1; off < 64; off <<= 1) {
        unsigned t = __shfl_up(incl, off, 64);
        if ((tid & 63) >= off) incl += t;
    }
    if ((tid & 63) == 63) wsum[tid >> 6] = incl;
    __syncthreads();
    if (tid == 0) {
        unsigned a = 0;
        #pragma unroll
        for (int w = 0; w < TPB / 64; ++w) { woff[w] = a; a += wsum[w]; }
    }
    __syncthreads();
    if (tid < NB) lbase[tid] = incl - h + woff[tid >> 6];
    __syncthreads();

    // ---- issue global reservation atomic (staggered, padded 64B lines).
    //      Result is NOT consumed until after staging -> latency overlapped.
    unsigned myres = 0;
    int      rb    = 0;
    if (tid < NB) {
        int boff = (int)blockIdx.x;
        while (boff >= NB) boff -= NB;
        rb = tid + boff;
        if (rb >= NB) rb -= NB;
        myres = atomicAdd(&counters[rb * CSTRIDE], hist_sbase[rb]);
    }

    // ---- build records (pure ALU, no memory dependency) + stage sorted ----
    #pragma unroll
    for (int r = 0; r < RPT; ++r) {
        if (cc_[r] >= 0) {
            unsigned b    = meta[r] >> 14;
            unsigned rank = meta[r] & 0x3FFFu;
            unsigned loc  = (unsigned)(cc_[r] - (int)b * CPB);
            unsigned p    = lbase[b] + rank;
            srec[p] = ((unsigned)vv_[r] << 12) | polbit | loc;
            sbid[p] = (unsigned short)b;
        }
    }
    if (tid < NB) hist_sbase[rb] = myres;   // reservation return lands here
    __syncthreads();

    // ---- coalesced writeout (consecutive p -> consecutive global) ----
    for (int p = tid; p < n; p += TPB) {
        unsigned b = sbid[p];
        recs[(size_t)b * CAP + hist_sbase[b] + ((unsigned)p - lbase[b])] = srec[p];
    }
}

// ---------------------------------------------------------------------------
// Bucket phase: one block per bucket (500 blocks -> 2/CU, 32 waves).
// Each thread loads its 3 uint4 record packs and issues all 12 x-gathers
// BEFORE the first use -> gather latency hidden by MLP + 32 waves/CU.
// Literal is quantized exactly as the old partition did -> bit-identical.
// ---------------------------------------------------------------------------
__global__ __launch_bounds__(1024, 8)
void bucket_loss_kernel(const uint4* __restrict__ recs4,
                        const float* __restrict__ x,
                        const float* __restrict__ cc,
                        float* __restrict__ partials) {
    __shared__ unsigned lacc[CPB];   // 8 KB
    const int b   = blockIdx.x;
    const int tid = (int)threadIdx.x;
    for (int j = tid; j < CPB; j += 1024) lacc[j] = 0;
    __syncthreads();

    // CAP/4 = 3000 uint4 per bucket: indices tid, tid+1024, tid+2048(<3000).
    const uint4* r4 = recs4 + (size_t)b * (CAP / 4);
    uint4 e0 = r4[tid];
    uint4 e1 = r4[tid + 1024];
    const bool has2 = (tid + 2048) < (CAP / 4);
    uint4 e2 = has2 ? r4[tid + 2048] : e0;   // dummy = e0 (valid indices)

    // Issue all 12 gathers up front.
    float a0 = x[e0.x >> 12], a1 = x[e0.y >> 12], a2 = x[e0.z >> 12], a3 = x[e0.w >> 12];
    float b0 = x[e1.x >> 12], b1 = x[e1.y >> 12], b2 = x[e1.z >> 12], b3 = x[e1.w >> 12];
    float c0 = x[e2.x >> 12], c1 = x[e2.y >> 12], c2 = x[e2.z >> 12], c3 = x[e2.w >> 12];

    #define PROC(r, xv, act)                                               \
        do { if (act) {                                                    \
            float lit = ((r) & 0x800u) ? (1.0f - (xv)) : (xv);             \
            unsigned q = (unsigned)(lit * QSCALE + 0.5f);                  \
            float lq = (float)q * QINV;                                    \
            float w  = __expf(Pc * lq);                                    \
            atomicAdd(&lacc[(r) & 0x7FFu], pack_fx(lq * w, w));            \
        } } while (0)

    PROC(e0.x, a0, true); PROC(e0.y, a1, true); PROC(e0.z, a2, true); PROC(e0.w, a3, true);
    PROC(e1.x, b0, true); PROC(e1.y, b1, true); PROC(e1.z, b2, true); PROC(e1.w, b3, true);
    PROC(e2.x, c0, has2); PROC(e2.y, c1, has2); PROC(e2.z, c2, has2); PROC(e2.w, c3, has2);
    #undef PROC
    __syncthreads();

    float v = 0.0f;
    const float* gc = cc + (size_t)b * CPB;
    for (int j = tid; j < CPB; j += 1024) {
        unsigned a   = lacc[j];                 // packed fields can't overflow
        float    num = (float)(a & 0xffffu) * FXINV;
        float    den = (float)(a >> 16)     * FXINV;
        float    sm  = 1.0f / (1.0f + __expf(-Ac * (num / den - 0.5f)));
        float    e0f = sm - gc[j];
        v += e0f * e0f;
    }
    v *= 1.0f / (float)NUM_CLAUSES;

    #pragma unroll
    for (int off = 32; off > 0; off >>= 1)
        v += __shfl_down(v, off, 64);

    __shared__ float partial[16];   // 1024 threads = 16 waves
    int lane = tid & 63;
    int wid  = tid >> 6;
    if (lane == 0) partial[wid] = v;
    __syncthreads();
    if (tid == 0) {
        float s = 0.f;
        #pragma unroll
        for (int w = 0; w < 16; ++w) s += partial[w];
        partials[b] = s;
    }
}

// ---------------------------------------------------------------------------
// Final reduce: ONE block sums NB partials, plain-stores out[0].
// ---------------------------------------------------------------------------
__global__ void final_kernel(const float* __restrict__ partials,
                             float* __restrict__ out, int n) {
    float v = 0.0f;
    for (int i = threadIdx.x; i < n; i += 256) v += partials[i];

    #pragma unroll
    for (int off = 32; off > 0; off >>= 1)
        v += __shfl_down(v, off, 64);

    __shared__ float partial[4];
    int lane = threadIdx.x & 63;
    int wid  = threadIdx.x >> 6;
    if (lane == 0) partial[wid] = v;
    __syncthreads();
    if (threadIdx.x == 0)
        out[0] = partial[0] + partial[1] + partial[2] + partial[3];
}

// ---------------------------------------------------------------------------
extern "C" void kernel_launch(void* const* d_in, const int* in_sizes, int n_in,
                              void* d_out, int out_size, void* d_ws, size_t ws_size,
                              hipStream_t stream) {
    const float* xv      = (const float*)d_in[0];   // [V] fp32
    const int*   adj_pos = (const int*)  d_in[1];   // [2,E] int32
    const int*   adj_neg = (const int*)  d_in[2];   // [2,E] int32
    const float* cc      = (const float*)d_in[3];   // [C] fp32 (ones)

    char* ws = (char*)d_ws;
    unsigned* recs     = (unsigned*)ws;
    unsigned* counters = (unsigned*)(ws + OFF_CTR);
    float*    partials = (float*)   (ws + OFF_PAR);
    float*    out      = (float*)d_out;

    // 1) zero padded bucket counters (32 KB)
    hipMemsetAsync(counters, 0, (size_t)NB * CSTRIDE * sizeof(unsigned), stream);

    // 2) partition both polarities into bucketed u32 records (no gathers)
    partition_kernel<<<2 * NBLKP, TPB, 0, stream>>>(adj_pos, adj_neg,
                                                    recs, counters);

    // 3) per-bucket gather + LDS accumulate + loss -> one partial per bucket
    bucket_loss_kernel<<<NB, 1024, 0, stream>>>((const uint4*)recs, xv, cc,
                                                partials);

    // 4) single-block final reduce -> out[0]
    final_kernel<<<1, 256, 0, stream>>>(partials, out, NB);
}